// Round 8
// baseline (913.888 us; speedup 1.0000x reference)
//
#include <hip/hip_runtime.h>

// VGAE encoder forward, all f32.
// R8: kill the CSR. R5-R7 showed 8B scatter writes never merge when ~100K
// row-fronts are open (working set >> L2); amplification is structural at
// that granularity. Fix the granularity instead:
//  (1) k_bin: bin edges into 782 buckets (row>>7) with block-local 2-pass
//      placement -> only 782 open write fronts (~50KB) -> full-line merging.
//      Payload packed {lr(7b)|col(17b), val} = 8B/edge.
//  (2) k_spmm_*: one workgroup per bucket; 128x16 output tile lives in LDS
//      (acc[128][17], ds_add_f32 atomics). Edges stream coalesced; H rows
//      gather as 64B group reads. No global atomics, no CSR materialized.
//      Epilogues keep R7's fusion (relu+W2|W3, reparam+output).
//
// Stages: memset bcur | k_bin | k_xw1 | k_spmm_d23 | k_spmm_out

#define SH    7              // rows per bucket = 128
#define BROWS 128
#define NBKT_MAX 800         // runtime nbkt = (N+127)>>7 = 782 for N=100000
#define CAP   4864           // bucket capacity; mean 4092, sigma~64 -> +12 sigma

// Phase A: bin edges by bucket = row>>SH. Two passes per block: LDS hist,
// one global atomicAdd per (block,bucket) to reserve, then placed writes.
__global__ __launch_bounds__(256)
void k_bin(const int* __restrict__ er, const int* __restrict__ ec,
           const float* __restrict__ ev, int* __restrict__ bcur,
           uint2* __restrict__ binned, int E, int nbkt) {
    __shared__ int lhist[NBKT_MAX];
    __shared__ int lbase[NBKT_MAX];
    __shared__ int lrank[NBKT_MAX];
    const int chunk = (E + gridDim.x - 1) / gridDim.x;
    const int lo = blockIdx.x * chunk;
    const int hi = min(lo + chunk, E);
    for (int t = threadIdx.x; t < nbkt; t += 256) { lhist[t] = 0; lrank[t] = 0; }
    __syncthreads();
    for (int e = lo + threadIdx.x; e < hi; e += 256)
        atomicAdd(&lhist[er[e] >> SH], 1);
    __syncthreads();
    for (int t = threadIdx.x; t < nbkt; t += 256) {
        int n = lhist[t];
        lbase[t] = n ? atomicAdd(&bcur[t], n) : 0;
    }
    __syncthreads();
    for (int e = lo + threadIdx.x; e < hi; e += 256) {
        int r = er[e];
        int b = r >> SH;
        int pos = lbase[b] + atomicAdd(&lrank[b], 1);
        if (pos < CAP) {
            unsigned pack = ((unsigned)(r & (BROWS - 1)) << 17) | (unsigned)ec[e];
            binned[(size_t)b * CAP + pos] = make_uint2(pack, __float_as_uint(ev[e]));
        }
    }
}

// XW1 = X @ W1.  Wave-per-row; lane L owns k in {4L..4L+3, 256+4L..256+4L+3}.
// __launch_bounds__(256, 2): 256-VGPR budget so w[8][16] stays in registers.
__global__ __launch_bounds__(256, 2)
void k_xw1(const float* __restrict__ X, const float* __restrict__ W1,
           float* __restrict__ out, int N) {
    const int lane = threadIdx.x & 63;
    const int wave  = (blockIdx.x * blockDim.x + threadIdx.x) >> 6;
    const int nwave = (gridDim.x * blockDim.x) >> 6;

    float w[8][16];
#pragma unroll
    for (int j = 0; j < 4; ++j) {
#pragma unroll
        for (int h4 = 0; h4 < 4; ++h4) {
            float4 a = *reinterpret_cast<const float4*>(W1 + (lane * 4 + j) * 16 + h4 * 4);
            w[j][h4*4+0] = a.x; w[j][h4*4+1] = a.y; w[j][h4*4+2] = a.z; w[j][h4*4+3] = a.w;
            float4 b = *reinterpret_cast<const float4*>(W1 + (256 + lane * 4 + j) * 16 + h4 * 4);
            w[4+j][h4*4+0] = b.x; w[4+j][h4*4+1] = b.y; w[4+j][h4*4+2] = b.z; w[4+j][h4*4+3] = b.w;
        }
    }

    const int l4 = lane & 15;
    const int hrev = ((l4 & 1) << 3) | ((l4 & 2) << 1) | ((l4 & 4) >> 1) | ((l4 & 8) >> 3);

    const float4* X4 = reinterpret_cast<const float4*>(X);

    int row = wave;
    if (row >= N) return;
    float4 xa = X4[(size_t)row * 128 + lane];
    float4 xb = X4[(size_t)row * 128 + 64 + lane];

    for (; row < N; row += nwave) {
        int nrow = row + nwave;
        float4 na, nb;
        if (nrow < N) {
            na = X4[(size_t)nrow * 128 + lane];
            nb = X4[(size_t)nrow * 128 + 64 + lane];
        }

        float a[16];
#pragma unroll
        for (int h = 0; h < 16; ++h) {
            a[h] = xa.x * w[0][h] + xa.y * w[1][h] + xa.z * w[2][h] + xa.w * w[3][h]
                 + xb.x * w[4][h] + xb.y * w[5][h] + xb.z * w[6][h] + xb.w * w[7][h];
        }

#define XW1_STEP(m, half)                                                  \
        {                                                                  \
            const bool hi_ = (lane & (m)) != 0;                            \
            _Pragma("unroll")                                              \
            for (int i = 0; i < (half); ++i) {                             \
                float send = hi_ ? a[i] : a[(half) + i];                   \
                float keep = hi_ ? a[(half) + i] : a[i];                   \
                a[i] = keep + __shfl_xor(send, (m));                       \
            }                                                              \
        }
        XW1_STEP(1, 8)
        XW1_STEP(2, 4)
        XW1_STEP(4, 2)
        XW1_STEP(8, 1)
#undef XW1_STEP
        a[0] += __shfl_xor(a[0], 16);
        a[0] += __shfl_xor(a[0], 32);

        if (lane < 16) out[(size_t)row * 16 + hrev] = a[0];

        xa = na; xb = nb;
    }
}

// Bucket SpMM + relu + [W2|W3] head. One workgroup per bucket; acc in LDS.
// 16-lane groups: load 16 edges coalesced, shfl-broadcast each, gather the
// 64B H row, ds_add_f32 into acc[lr][f]. Epilogue: M[row][f] =
// sum_k relu(acc[row][k]) * Wcol[k][f]  (f<7: W2, 7<=f<14: W3, else 0).
__global__ __launch_bounds__(256)
void k_spmm_d23(const uint2* __restrict__ binned, const int* __restrict__ bcur,
                const float* __restrict__ H, const float* __restrict__ W2,
                const float* __restrict__ W3, float* __restrict__ M, int N) {
    __shared__ float acc[BROWS][17];
    const int b   = blockIdx.x;
    const int tid = threadIdx.x;
    const int f   = tid & 15;
    const int g16 = tid >> 4;   // 16 groups of 16 lanes

    for (int i = tid; i < BROWS * 17; i += 256) (&acc[0][0])[i] = 0.f;

    float wcol[16];
    if (f < 7) {
#pragma unroll
        for (int k = 0; k < 16; ++k) wcol[k] = W2[k * 7 + f];
    } else if (f < 14) {
#pragma unroll
        for (int k = 0; k < 16; ++k) wcol[k] = W3[k * 7 + (f - 7)];
    } else {
#pragma unroll
        for (int k = 0; k < 16; ++k) wcol[k] = 0.f;
    }
    __syncthreads();

    const int cnt = min(bcur[b], CAP);
    const uint2* eb = binned + (size_t)b * CAP;
    for (int j0 = g16 * 16; j0 < cnt; j0 += 256) {
        int j = j0 + f;
        uint2 e = (j < cnt) ? eb[j] : make_uint2(0u, 0u);
        const int nvalid = min(cnt - j0, 16);   // group-uniform
#pragma unroll 4
        for (int u = 0; u < 16; ++u) {
            if (u >= nvalid) break;
            unsigned pk = __shfl(e.x, u, 16);
            float    vv = __uint_as_float(__shfl(e.y, u, 16));
            int lr  = pk >> 17;
            int col = pk & 0x1FFFF;
            float hv = H[(size_t)col * 16 + f];
            atomicAdd(&acc[lr][f], vv * hv);
        }
    }
    __syncthreads();

    const int rbase = b << SH;
#pragma unroll
    for (int t = 0; t < BROWS; t += 16) {
        int lr = t + g16;
        int row = rbase + lr;
        if (row < N) {
            float o = 0.f;
#pragma unroll
            for (int k = 0; k < 16; ++k) o += fmaxf(acc[lr][k], 0.f) * wcol[k];
            M[(size_t)row * 16 + f] = o;
        }
    }
}

// Bucket SpMM + reparameterization epilogue: out[row][f] =
// acc[row][f] + eps[row][f] * exp(acc[row][f+7])  for f < 7.
__global__ __launch_bounds__(256)
void k_spmm_out(const uint2* __restrict__ binned, const int* __restrict__ bcur,
                const float* __restrict__ H, const float* __restrict__ eps,
                float* __restrict__ out, int N) {
    __shared__ float acc[BROWS][17];
    const int b   = blockIdx.x;
    const int tid = threadIdx.x;
    const int f   = tid & 15;
    const int g16 = tid >> 4;

    for (int i = tid; i < BROWS * 17; i += 256) (&acc[0][0])[i] = 0.f;
    __syncthreads();

    const int cnt = min(bcur[b], CAP);
    const uint2* eb = binned + (size_t)b * CAP;
    for (int j0 = g16 * 16; j0 < cnt; j0 += 256) {
        int j = j0 + f;
        uint2 e = (j < cnt) ? eb[j] : make_uint2(0u, 0u);
        const int nvalid = min(cnt - j0, 16);
#pragma unroll 4
        for (int u = 0; u < 16; ++u) {
            if (u >= nvalid) break;
            unsigned pk = __shfl(e.x, u, 16);
            float    vv = __uint_as_float(__shfl(e.y, u, 16));
            int lr  = pk >> 17;
            int col = pk & 0x1FFFF;
            float hv = H[(size_t)col * 16 + f];
            atomicAdd(&acc[lr][f], vv * hv);
        }
    }
    __syncthreads();

    const int rbase = b << SH;
#pragma unroll
    for (int t = 0; t < BROWS; t += 16) {
        int lr = t + g16;
        int row = rbase + lr;
        if (row < N && f < 7) {
            float zm = acc[lr][f];
            float ls = acc[lr][f + 7];
            out[(size_t)row * 7 + f] = zm + eps[(size_t)row * 7 + f] * __expf(ls);
        }
    }
}

extern "C" void kernel_launch(void* const* d_in, const int* in_sizes, int n_in,
                              void* d_out, int out_size, void* d_ws, size_t ws_size,
                              hipStream_t stream) {
    const float* X   = (const float*)d_in[0];
    const int*   er  = (const int*)d_in[1];
    const int*   ec  = (const int*)d_in[2];
    const float* ev  = (const float*)d_in[3];
    const float* W1  = (const float*)d_in[4];
    const float* W2  = (const float*)d_in[5];
    const float* W3  = (const float*)d_in[6];
    const float* eps = (const float*)d_in[7];
    float* out = (float*)d_out;

    const int N    = in_sizes[0] / 512;
    const int E    = in_sizes[1];
    const int nbkt = (N + BROWS - 1) >> SH;   // 782 for N=100000 (<= NBKT_MAX)

    // workspace layout
    float* ws     = (float*)d_ws;
    float* XW1    = ws;                          // N*16 f32
    float* M23    = ws + (size_t)N * 16;         // N*16 f32
    int*   bcur   = (int*)(ws + (size_t)N * 32); // nbkt i32 (pad to 1024)
    uint2* binned = (uint2*)(ws + (size_t)N * 32 + 1024); // nbkt*CAP*8 B

    hipMemsetAsync(bcur, 0, (size_t)nbkt * sizeof(int), stream);
    k_bin     <<<512, 256, 0, stream>>>(er, ec, ev, bcur, binned, E, nbkt);
    k_xw1     <<<2048, 256, 0, stream>>>(X, W1, XW1, N);
    k_spmm_d23<<<nbkt, 256, 0, stream>>>(binned, bcur, XW1, W2, W3, M23, N);
    k_spmm_out<<<nbkt, 256, 0, stream>>>(binned, bcur, M23, eps, out, N);
}

// Round 9
// 854.397 us; speedup vs baseline: 1.0696x; 1.0696x over previous
//
#include <hip/hip_runtime.h>

// VGAE encoder forward, all f32.
// R9: R8's bucket binning VALIDATED the write-merging theory (WRITE 161MB ->
// 6MB) but the bucket SpMM was latency-serialized: per-16-lane-group serial
// shfl->gather->atomic chain, only 12.5K groups -> 380us at 4% VALU.
// Fix the execution model, keep the structure: 4-lanes-per-edge push. Edge
// uint2 read broadcast across 4 lanes; each lane gathers one float4 quarter
// of the H row (64B line coalesced); 4 independent ds_add_f32 into
// acc[lr][q*4..]. Independent j-iterations + unroll -> deep MLP.
// k_bin / k_xw1 / epilogues unchanged (single-variable experiment).
//
// Stages: memset bcur | k_bin | k_xw1 | k_spmm_d23 | k_spmm_out

#define SH    7              // rows per bucket = 128
#define BROWS 128
#define NBKT_MAX 800         // runtime nbkt = (N+127)>>7 = 782 for N=100000
#define CAP   4864           // bucket capacity; mean 4092, sigma~64 -> +12 sigma

// Phase A: bin edges by bucket = row>>SH. Two passes per block: LDS hist,
// one global atomicAdd per (block,bucket) to reserve, then placed writes.
__global__ __launch_bounds__(256)
void k_bin(const int* __restrict__ er, const int* __restrict__ ec,
           const float* __restrict__ ev, int* __restrict__ bcur,
           uint2* __restrict__ binned, int E, int nbkt) {
    __shared__ int lhist[NBKT_MAX];
    __shared__ int lbase[NBKT_MAX];
    __shared__ int lrank[NBKT_MAX];
    const int chunk = (E + gridDim.x - 1) / gridDim.x;
    const int lo = blockIdx.x * chunk;
    const int hi = min(lo + chunk, E);
    for (int t = threadIdx.x; t < nbkt; t += 256) { lhist[t] = 0; lrank[t] = 0; }
    __syncthreads();
    for (int e = lo + threadIdx.x; e < hi; e += 256)
        atomicAdd(&lhist[er[e] >> SH], 1);
    __syncthreads();
    for (int t = threadIdx.x; t < nbkt; t += 256) {
        int n = lhist[t];
        lbase[t] = n ? atomicAdd(&bcur[t], n) : 0;
    }
    __syncthreads();
    for (int e = lo + threadIdx.x; e < hi; e += 256) {
        int r = er[e];
        int b = r >> SH;
        int pos = lbase[b] + atomicAdd(&lrank[b], 1);
        if (pos < CAP) {
            unsigned pack = ((unsigned)(r & (BROWS - 1)) << 17) | (unsigned)ec[e];
            binned[(size_t)b * CAP + pos] = make_uint2(pack, __float_as_uint(ev[e]));
        }
    }
}

// XW1 = X @ W1.  Wave-per-row; lane L owns k in {4L..4L+3, 256+4L..256+4L+3}.
// __launch_bounds__(256, 2): 256-VGPR budget so w[8][16] stays in registers.
__global__ __launch_bounds__(256, 2)
void k_xw1(const float* __restrict__ X, const float* __restrict__ W1,
           float* __restrict__ out, int N) {
    const int lane = threadIdx.x & 63;
    const int wave  = (blockIdx.x * blockDim.x + threadIdx.x) >> 6;
    const int nwave = (gridDim.x * blockDim.x) >> 6;

    float w[8][16];
#pragma unroll
    for (int j = 0; j < 4; ++j) {
#pragma unroll
        for (int h4 = 0; h4 < 4; ++h4) {
            float4 a = *reinterpret_cast<const float4*>(W1 + (lane * 4 + j) * 16 + h4 * 4);
            w[j][h4*4+0] = a.x; w[j][h4*4+1] = a.y; w[j][h4*4+2] = a.z; w[j][h4*4+3] = a.w;
            float4 b = *reinterpret_cast<const float4*>(W1 + (256 + lane * 4 + j) * 16 + h4 * 4);
            w[4+j][h4*4+0] = b.x; w[4+j][h4*4+1] = b.y; w[4+j][h4*4+2] = b.z; w[4+j][h4*4+3] = b.w;
        }
    }

    const int l4 = lane & 15;
    const int hrev = ((l4 & 1) << 3) | ((l4 & 2) << 1) | ((l4 & 4) >> 1) | ((l4 & 8) >> 3);

    const float4* X4 = reinterpret_cast<const float4*>(X);

    int row = wave;
    if (row >= N) return;
    float4 xa = X4[(size_t)row * 128 + lane];
    float4 xb = X4[(size_t)row * 128 + 64 + lane];

    for (; row < N; row += nwave) {
        int nrow = row + nwave;
        float4 na, nb;
        if (nrow < N) {
            na = X4[(size_t)nrow * 128 + lane];
            nb = X4[(size_t)nrow * 128 + 64 + lane];
        }

        float a[16];
#pragma unroll
        for (int h = 0; h < 16; ++h) {
            a[h] = xa.x * w[0][h] + xa.y * w[1][h] + xa.z * w[2][h] + xa.w * w[3][h]
                 + xb.x * w[4][h] + xb.y * w[5][h] + xb.z * w[6][h] + xb.w * w[7][h];
        }

#define XW1_STEP(m, half)                                                  \
        {                                                                  \
            const bool hi_ = (lane & (m)) != 0;                            \
            _Pragma("unroll")                                              \
            for (int i = 0; i < (half); ++i) {                             \
                float send = hi_ ? a[i] : a[(half) + i];                   \
                float keep = hi_ ? a[(half) + i] : a[i];                   \
                a[i] = keep + __shfl_xor(send, (m));                       \
            }                                                              \
        }
        XW1_STEP(1, 8)
        XW1_STEP(2, 4)
        XW1_STEP(4, 2)
        XW1_STEP(8, 1)
#undef XW1_STEP
        a[0] += __shfl_xor(a[0], 16);
        a[0] += __shfl_xor(a[0], 32);

        if (lane < 16) out[(size_t)row * 16 + hrev] = a[0];

        xa = na; xb = nb;
    }
}

// Bucket SpMM v2 (4 lanes per edge) + relu + [W2|W3] head epilogue.
__global__ __launch_bounds__(256)
void k_spmm_d23(const uint2* __restrict__ binned, const int* __restrict__ bcur,
                const float* __restrict__ H, const float* __restrict__ W2,
                const float* __restrict__ W3, float* __restrict__ M, int N) {
    __shared__ float acc[BROWS][17];
    const int b   = blockIdx.x;
    const int tid = threadIdx.x;
    const int es  = tid >> 2;   // 64 edge slots
    const int q   = tid & 3;    // float4 quarter of the H row

    for (int i = tid; i < BROWS * 17; i += 256) (&acc[0][0])[i] = 0.f;
    __syncthreads();

    const int cnt = min(bcur[b], CAP);
    const uint2* eb = binned + (size_t)b * CAP;
#pragma unroll 4
    for (int j = es; j < cnt; j += 64) {
        uint2 e = eb[j];                       // 4 lanes same addr -> broadcast
        int lr  = e.x >> 17;
        int col = e.x & 0x1FFFF;
        float v = __uint_as_float(e.y);
        float4 h = *reinterpret_cast<const float4*>(H + (size_t)col * 16 + q * 4);
        atomicAdd(&acc[lr][q * 4 + 0], v * h.x);
        atomicAdd(&acc[lr][q * 4 + 1], v * h.y);
        atomicAdd(&acc[lr][q * 4 + 2], v * h.z);
        atomicAdd(&acc[lr][q * 4 + 3], v * h.w);
    }
    __syncthreads();

    // epilogue: M[row][f] = sum_k relu(acc[row][k]) * Wcol[k][f]
    const int f   = tid & 15;
    const int g16 = tid >> 4;
    float wcol[16];
    if (f < 7) {
#pragma unroll
        for (int k = 0; k < 16; ++k) wcol[k] = W2[k * 7 + f];
    } else if (f < 14) {
#pragma unroll
        for (int k = 0; k < 16; ++k) wcol[k] = W3[k * 7 + (f - 7)];
    } else {
#pragma unroll
        for (int k = 0; k < 16; ++k) wcol[k] = 0.f;
    }
    const int rbase = b << SH;
#pragma unroll
    for (int t = 0; t < BROWS; t += 16) {
        int lr = t + g16;
        int row = rbase + lr;
        if (row < N) {
            float o = 0.f;
#pragma unroll
            for (int k = 0; k < 16; ++k) o += fmaxf(acc[lr][k], 0.f) * wcol[k];
            M[(size_t)row * 16 + f] = o;
        }
    }
}

// Bucket SpMM v2 (4 lanes per edge) + reparameterization epilogue.
__global__ __launch_bounds__(256)
void k_spmm_out(const uint2* __restrict__ binned, const int* __restrict__ bcur,
                const float* __restrict__ H, const float* __restrict__ eps,
                float* __restrict__ out, int N) {
    __shared__ float acc[BROWS][17];
    const int b   = blockIdx.x;
    const int tid = threadIdx.x;
    const int es  = tid >> 2;
    const int q   = tid & 3;

    for (int i = tid; i < BROWS * 17; i += 256) (&acc[0][0])[i] = 0.f;
    __syncthreads();

    const int cnt = min(bcur[b], CAP);
    const uint2* eb = binned + (size_t)b * CAP;
#pragma unroll 4
    for (int j = es; j < cnt; j += 64) {
        uint2 e = eb[j];
        int lr  = e.x >> 17;
        int col = e.x & 0x1FFFF;
        float v = __uint_as_float(e.y);
        float4 h = *reinterpret_cast<const float4*>(H + (size_t)col * 16 + q * 4);
        atomicAdd(&acc[lr][q * 4 + 0], v * h.x);
        atomicAdd(&acc[lr][q * 4 + 1], v * h.y);
        atomicAdd(&acc[lr][q * 4 + 2], v * h.z);
        atomicAdd(&acc[lr][q * 4 + 3], v * h.w);
    }
    __syncthreads();

    const int f   = tid & 15;
    const int g16 = tid >> 4;
    const int rbase = b << SH;
#pragma unroll
    for (int t = 0; t < BROWS; t += 16) {
        int lr = t + g16;
        int row = rbase + lr;
        if (row < N && f < 7) {
            float zm = acc[lr][f];
            float ls = acc[lr][f + 7];
            out[(size_t)row * 7 + f] = zm + eps[(size_t)row * 7 + f] * __expf(ls);
        }
    }
}

extern "C" void kernel_launch(void* const* d_in, const int* in_sizes, int n_in,
                              void* d_out, int out_size, void* d_ws, size_t ws_size,
                              hipStream_t stream) {
    const float* X   = (const float*)d_in[0];
    const int*   er  = (const int*)d_in[1];
    const int*   ec  = (const int*)d_in[2];
    const float* ev  = (const float*)d_in[3];
    const float* W1  = (const float*)d_in[4];
    const float* W2  = (const float*)d_in[5];
    const float* W3  = (const float*)d_in[6];
    const float* eps = (const float*)d_in[7];
    float* out = (float*)d_out;

    const int N    = in_sizes[0] / 512;
    const int E    = in_sizes[1];
    const int nbkt = (N + BROWS - 1) >> SH;   // 782 for N=100000 (<= NBKT_MAX)

    // workspace layout
    float* ws     = (float*)d_ws;
    float* XW1    = ws;                          // N*16 f32
    float* M23    = ws + (size_t)N * 16;         // N*16 f32
    int*   bcur   = (int*)(ws + (size_t)N * 32); // nbkt i32 (pad to 1024)
    uint2* binned = (uint2*)(ws + (size_t)N * 32 + 1024); // nbkt*CAP*8 B

    hipMemsetAsync(bcur, 0, (size_t)nbkt * sizeof(int), stream);
    k_bin     <<<512, 256, 0, stream>>>(er, ec, ev, bcur, binned, E, nbkt);
    k_xw1     <<<2048, 256, 0, stream>>>(X, W1, XW1, N);
    k_spmm_d23<<<nbkt, 256, 0, stream>>>(binned, bcur, XW1, W2, W3, M23, N);
    k_spmm_out<<<nbkt, 256, 0, stream>>>(binned, bcur, M23, eps, out, N);
}

// Round 10
// 332.959 us; speedup vs baseline: 2.7447x; 2.5661x over previous
//
#include <hip/hip_runtime.h>

// VGAE encoder forward, all f32.
// R10: bucket layout validated (R8: WRITE 161MB->6MB) but bucket SpMM was
// latency-starved: random H gathers miss L2 ~50% (FETCH=100MB=1.6M x 64B),
// only 12 waves/CU to hide it, + 51.2M LDS atomics. v3 execution model:
//  - 1024 thr/block (16 waves, 2 blocks/CU = 100% occupancy)
//  - in-LDS counting sort of the bucket by local row (stash in regs, hist,
//    7-step scan, rank-place) -> sorted se[CAP] in LDS
//  - then R7's proven 16-lane-per-row REGISTER pull straight from LDS:
//    zero per-feature atomics, fused epilogues unchanged.
// Also: k_bin grid 512->1024 (was 25% occupancy, pure TLP fix).
//
// Stages: memset bcur | k_bin | k_xw1 | k_spmm_d23 | k_spmm_out

#define SH    7              // rows per bucket = 128
#define BROWS 128
#define NBKT_MAX 800         // runtime nbkt = (N+127)>>7 = 782 for N=100000
#define CAP   4864           // bucket capacity; mean 4092, sigma~64 -> +12 sigma

// Phase A: bin edges by bucket = row>>SH. Two passes per block: LDS hist,
// one global atomicAdd per (block,bucket) to reserve, then placed writes.
__global__ __launch_bounds__(256)
void k_bin(const int* __restrict__ er, const int* __restrict__ ec,
           const float* __restrict__ ev, int* __restrict__ bcur,
           uint2* __restrict__ binned, int E, int nbkt) {
    __shared__ int lhist[NBKT_MAX];
    __shared__ int lbase[NBKT_MAX];
    __shared__ int lrank[NBKT_MAX];
    const int chunk = (E + gridDim.x - 1) / gridDim.x;
    const int lo = blockIdx.x * chunk;
    const int hi = min(lo + chunk, E);
    for (int t = threadIdx.x; t < nbkt; t += 256) { lhist[t] = 0; lrank[t] = 0; }
    __syncthreads();
    for (int e = lo + threadIdx.x; e < hi; e += 256)
        atomicAdd(&lhist[er[e] >> SH], 1);
    __syncthreads();
    for (int t = threadIdx.x; t < nbkt; t += 256) {
        int n = lhist[t];
        lbase[t] = n ? atomicAdd(&bcur[t], n) : 0;
    }
    __syncthreads();
    for (int e = lo + threadIdx.x; e < hi; e += 256) {
        int r = er[e];
        int b = r >> SH;
        int pos = lbase[b] + atomicAdd(&lrank[b], 1);
        if (pos < CAP) {
            unsigned pack = ((unsigned)(r & (BROWS - 1)) << 17) | (unsigned)ec[e];
            binned[(size_t)b * CAP + pos] = make_uint2(pack, __float_as_uint(ev[e]));
        }
    }
}

// XW1 = X @ W1.  Wave-per-row; lane L owns k in {4L..4L+3, 256+4L..256+4L+3}.
// __launch_bounds__(256, 2): 256-VGPR budget so w[8][16] stays in registers.
__global__ __launch_bounds__(256, 2)
void k_xw1(const float* __restrict__ X, const float* __restrict__ W1,
           float* __restrict__ out, int N) {
    const int lane = threadIdx.x & 63;
    const int wave  = (blockIdx.x * blockDim.x + threadIdx.x) >> 6;
    const int nwave = (gridDim.x * blockDim.x) >> 6;

    float w[8][16];
#pragma unroll
    for (int j = 0; j < 4; ++j) {
#pragma unroll
        for (int h4 = 0; h4 < 4; ++h4) {
            float4 a = *reinterpret_cast<const float4*>(W1 + (lane * 4 + j) * 16 + h4 * 4);
            w[j][h4*4+0] = a.x; w[j][h4*4+1] = a.y; w[j][h4*4+2] = a.z; w[j][h4*4+3] = a.w;
            float4 b = *reinterpret_cast<const float4*>(W1 + (256 + lane * 4 + j) * 16 + h4 * 4);
            w[4+j][h4*4+0] = b.x; w[4+j][h4*4+1] = b.y; w[4+j][h4*4+2] = b.z; w[4+j][h4*4+3] = b.w;
        }
    }

    const int l4 = lane & 15;
    const int hrev = ((l4 & 1) << 3) | ((l4 & 2) << 1) | ((l4 & 4) >> 1) | ((l4 & 8) >> 3);

    const float4* X4 = reinterpret_cast<const float4*>(X);

    int row = wave;
    if (row >= N) return;
    float4 xa = X4[(size_t)row * 128 + lane];
    float4 xb = X4[(size_t)row * 128 + 64 + lane];

    for (; row < N; row += nwave) {
        int nrow = row + nwave;
        float4 na, nb;
        if (nrow < N) {
            na = X4[(size_t)nrow * 128 + lane];
            nb = X4[(size_t)nrow * 128 + 64 + lane];
        }

        float a[16];
#pragma unroll
        for (int h = 0; h < 16; ++h) {
            a[h] = xa.x * w[0][h] + xa.y * w[1][h] + xa.z * w[2][h] + xa.w * w[3][h]
                 + xb.x * w[4][h] + xb.y * w[5][h] + xb.z * w[6][h] + xb.w * w[7][h];
        }

#define XW1_STEP(m, half)                                                  \
        {                                                                  \
            const bool hi_ = (lane & (m)) != 0;                            \
            _Pragma("unroll")                                              \
            for (int i = 0; i < (half); ++i) {                             \
                float send = hi_ ? a[i] : a[(half) + i];                   \
                float keep = hi_ ? a[(half) + i] : a[i];                   \
                a[i] = keep + __shfl_xor(send, (m));                       \
            }                                                              \
        }
        XW1_STEP(1, 8)
        XW1_STEP(2, 4)
        XW1_STEP(4, 2)
        XW1_STEP(8, 1)
#undef XW1_STEP
        a[0] += __shfl_xor(a[0], 16);
        a[0] += __shfl_xor(a[0], 32);

        if (lane < 16) out[(size_t)row * 16 + hrev] = a[0];

        xa = na; xb = nb;
    }
}

// ---- shared sort-then-pull machinery for the bucket SpMM kernels ----
// (macro-free inline: stash edges in regs, LDS hist+scan+place, giving
//  sorted se[] and row offsets lofs[]; then 64x16-lane register pulls.)

// Bucket SpMM v3 + relu + [W2|W3] head epilogue.
__global__ __launch_bounds__(1024)
void k_spmm_d23(const uint2* __restrict__ binned, const int* __restrict__ bcur,
                const float* __restrict__ H, const float* __restrict__ W2,
                const float* __restrict__ W3, float* __restrict__ M, int N) {
    __shared__ uint2 se[CAP];
    __shared__ int lhist[BROWS];
    __shared__ int lofs[BROWS + 1];
    __shared__ int lrank[BROWS];
    const int b   = blockIdx.x;
    const int tid = threadIdx.x;

    if (tid < BROWS) { lhist[tid] = 0; lrank[tid] = 0; }
    __syncthreads();

    const int cnt = min(bcur[b], CAP);
    const uint2* eb = binned + (size_t)b * CAP;

    // stash + hist (CAP/1024 = 4.75 -> 5 static slots)
    uint2 st[5]; int slr[5];
#pragma unroll
    for (int it = 0; it < 5; ++it) {
        int j = tid + it * 1024;
        if (j < cnt) {
            uint2 e = eb[j];
            st[it] = e;
            slr[it] = (int)(e.x >> 17);
            atomicAdd(&lhist[slr[it]], 1);
        } else slr[it] = -1;
    }
    __syncthreads();

    // exclusive offsets: lofs[0]=0, lofs[i+1]=incl-scan(lhist)[i]
    if (tid < BROWS) lofs[tid + 1] = lhist[tid];
    if (tid == 0) lofs[0] = 0;
    __syncthreads();
    for (int off = 1; off < BROWS; off <<= 1) {
        int v = (tid < BROWS && tid >= off) ? lofs[tid + 1 - off] : 0;
        __syncthreads();
        if (tid < BROWS) lofs[tid + 1] += v;
        __syncthreads();
    }

    // place into sorted order
#pragma unroll
    for (int it = 0; it < 5; ++it) {
        if (slr[it] >= 0) {
            int pos = lofs[slr[it]] + atomicAdd(&lrank[slr[it]], 1);
            se[pos] = st[it];
        }
    }
    __syncthreads();

    // register pull: 64 groups of 16 lanes; group g handles rows g, g+64
    const int f = tid & 15;
    const int g = tid >> 4;
    float wcol[16];
    if (f < 7) {
#pragma unroll
        for (int k = 0; k < 16; ++k) wcol[k] = W2[k * 7 + f];
    } else if (f < 14) {
#pragma unroll
        for (int k = 0; k < 16; ++k) wcol[k] = W3[k * 7 + (f - 7)];
    } else {
#pragma unroll
        for (int k = 0; k < 16; ++k) wcol[k] = 0.f;
    }
    const int rbase = b << SH;
#pragma unroll
    for (int rr = 0; rr < BROWS; rr += 64) {
        const int lr = rr + g;
        const int beg = lofs[lr], end = lofs[lr + 1];
        float acc = 0.f;
        for (int j = beg; j < end; ++j) {
            uint2 e = se[j];                       // LDS broadcast in group
            acc += __uint_as_float(e.y) * H[(size_t)(e.x & 0x1FFFF) * 16 + f];
        }
        float a = fmaxf(acc, 0.f);
        float o = 0.f;
#pragma unroll
        for (int k = 0; k < 16; ++k) o += __shfl(a, k, 16) * wcol[k];
        int row = rbase + lr;
        if (row < N) M[(size_t)row * 16 + f] = o;
    }
}

// Bucket SpMM v3 + reparameterization epilogue.
__global__ __launch_bounds__(1024)
void k_spmm_out(const uint2* __restrict__ binned, const int* __restrict__ bcur,
                const float* __restrict__ H, const float* __restrict__ eps,
                float* __restrict__ out, int N) {
    __shared__ uint2 se[CAP];
    __shared__ int lhist[BROWS];
    __shared__ int lofs[BROWS + 1];
    __shared__ int lrank[BROWS];
    const int b   = blockIdx.x;
    const int tid = threadIdx.x;

    if (tid < BROWS) { lhist[tid] = 0; lrank[tid] = 0; }
    __syncthreads();

    const int cnt = min(bcur[b], CAP);
    const uint2* eb = binned + (size_t)b * CAP;

    uint2 st[5]; int slr[5];
#pragma unroll
    for (int it = 0; it < 5; ++it) {
        int j = tid + it * 1024;
        if (j < cnt) {
            uint2 e = eb[j];
            st[it] = e;
            slr[it] = (int)(e.x >> 17);
            atomicAdd(&lhist[slr[it]], 1);
        } else slr[it] = -1;
    }
    __syncthreads();

    if (tid < BROWS) lofs[tid + 1] = lhist[tid];
    if (tid == 0) lofs[0] = 0;
    __syncthreads();
    for (int off = 1; off < BROWS; off <<= 1) {
        int v = (tid < BROWS && tid >= off) ? lofs[tid + 1 - off] : 0;
        __syncthreads();
        if (tid < BROWS) lofs[tid + 1] += v;
        __syncthreads();
    }

#pragma unroll
    for (int it = 0; it < 5; ++it) {
        if (slr[it] >= 0) {
            int pos = lofs[slr[it]] + atomicAdd(&lrank[slr[it]], 1);
            se[pos] = st[it];
        }
    }
    __syncthreads();

    const int f = tid & 15;
    const int g = tid >> 4;
    const int rbase = b << SH;
#pragma unroll
    for (int rr = 0; rr < BROWS; rr += 64) {
        const int lr = rr + g;
        const int beg = lofs[lr], end = lofs[lr + 1];
        float acc = 0.f;
        for (int j = beg; j < end; ++j) {
            uint2 e = se[j];
            acc += __uint_as_float(e.y) * H[(size_t)(e.x & 0x1FFFF) * 16 + f];
        }
        const int src = (f < 7) ? (f + 7) : f;
        float ls = __shfl(acc, src, 16);
        int row = rbase + lr;
        if (row < N && f < 7) {
            out[(size_t)row * 7 + f] = acc + eps[(size_t)row * 7 + f] * __expf(ls);
        }
    }
}

extern "C" void kernel_launch(void* const* d_in, const int* in_sizes, int n_in,
                              void* d_out, int out_size, void* d_ws, size_t ws_size,
                              hipStream_t stream) {
    const float* X   = (const float*)d_in[0];
    const int*   er  = (const int*)d_in[1];
    const int*   ec  = (const int*)d_in[2];
    const float* ev  = (const float*)d_in[3];
    const float* W1  = (const float*)d_in[4];
    const float* W2  = (const float*)d_in[5];
    const float* W3  = (const float*)d_in[6];
    const float* eps = (const float*)d_in[7];
    float* out = (float*)d_out;

    const int N    = in_sizes[0] / 512;
    const int E    = in_sizes[1];
    const int nbkt = (N + BROWS - 1) >> SH;   // 782 for N=100000 (<= NBKT_MAX)

    // workspace layout
    float* ws     = (float*)d_ws;
    float* XW1    = ws;                          // N*16 f32
    float* M23    = ws + (size_t)N * 16;         // N*16 f32
    int*   bcur   = (int*)(ws + (size_t)N * 32); // nbkt i32 (pad to 1024)
    uint2* binned = (uint2*)(ws + (size_t)N * 32 + 1024); // nbkt*CAP*8 B

    hipMemsetAsync(bcur, 0, (size_t)nbkt * sizeof(int), stream);
    k_bin     <<<1024, 256, 0, stream>>>(er, ec, ev, bcur, binned, E, nbkt);
    k_xw1     <<<2048, 256, 0, stream>>>(X, W1, XW1, N);
    k_spmm_d23<<<nbkt, 1024, 0, stream>>>(binned, bcur, XW1, W2, W3, M23, N);
    k_spmm_out<<<nbkt, 1024, 0, stream>>>(binned, bcur, M23, eps, out, N);
}

// Round 12
// 311.502 us; speedup vs baseline: 2.9338x; 1.0689x over previous
//
#include <hip/hip_runtime.h>

// VGAE encoder forward, all f32.
// R11b: same as R11 (fused bin+xw1, sort-once, nt loads) with the compile
// fix: __builtin_nontemporal_load can't take uint2* -> load the 8B edge
// record as unsigned long long and unpack.
//
// Stages: memset bcur | k_bin_xw1 | k_spmm_d23 | k_spmm_out

#define SH    7              // rows per bucket = 128
#define BROWS 128
#define NBKT_MAX 800         // runtime nbkt = (N+127)>>7 = 782 for N=100000
#define CAP   4864           // bucket capacity; mean 4092, sigma~64 -> +12 sigma
#define BINB  512            // binning blocks in the fused kernel
#define LOFS_STRIDE (BROWS + 4)

__device__ __forceinline__ uint2 nt_load_edge(const uint2* p) {
    unsigned long long v =
        __builtin_nontemporal_load(reinterpret_cast<const unsigned long long*>(p));
    return make_uint2((unsigned)v, (unsigned)(v >> 32));
}

// Fused binning (blocks [0,BINB)) + XW1 GEMM (blocks [BINB, BINB+nxw1)).
__global__ __launch_bounds__(256, 2)
void k_bin_xw1(const int* __restrict__ er, const int* __restrict__ ec,
               const float* __restrict__ ev, int* __restrict__ bcur,
               uint2* __restrict__ binned, int E, int nbkt,
               const float* __restrict__ X, const float* __restrict__ W1,
               float* __restrict__ XW1, int N) {
    __shared__ int lhist[NBKT_MAX];
    __shared__ int lbase[NBKT_MAX];
    __shared__ int lrank[NBKT_MAX];

    if (blockIdx.x < BINB) {
        // ---------------- binning path ----------------
        const int chunk = (E + BINB - 1) / BINB;
        const int lo = blockIdx.x * chunk;
        const int hi = min(lo + chunk, E);
        for (int t = threadIdx.x; t < nbkt; t += 256) { lhist[t] = 0; lrank[t] = 0; }
        __syncthreads();
        for (int e = lo + threadIdx.x; e < hi; e += 256)
            atomicAdd(&lhist[__builtin_nontemporal_load(&er[e]) >> SH], 1);
        __syncthreads();
        for (int t = threadIdx.x; t < nbkt; t += 256) {
            int n = lhist[t];
            lbase[t] = n ? atomicAdd(&bcur[t], n) : 0;
        }
        __syncthreads();
        for (int e = lo + threadIdx.x; e < hi; e += 256) {
            int r = __builtin_nontemporal_load(&er[e]);
            int b = r >> SH;
            int pos = lbase[b] + atomicAdd(&lrank[b], 1);
            if (pos < CAP) {
                int   c = __builtin_nontemporal_load(&ec[e]);
                float v = __builtin_nontemporal_load(&ev[e]);
                unsigned pack = ((unsigned)(r & (BROWS - 1)) << 17) | (unsigned)c;
                binned[(size_t)b * CAP + pos] = make_uint2(pack, __float_as_uint(v));
            }
        }
        return;
    }

    // ---------------- XW1 path ----------------
    const int lane = threadIdx.x & 63;
    const int bid  = blockIdx.x - BINB;
    const int nxb  = gridDim.x - BINB;
    const int wave  = (bid * 256 + (int)threadIdx.x) >> 6;
    const int nwave = nxb * 4;

    float w[8][16];
#pragma unroll
    for (int j = 0; j < 4; ++j) {
#pragma unroll
        for (int h4 = 0; h4 < 4; ++h4) {
            float4 a = *reinterpret_cast<const float4*>(W1 + (lane * 4 + j) * 16 + h4 * 4);
            w[j][h4*4+0] = a.x; w[j][h4*4+1] = a.y; w[j][h4*4+2] = a.z; w[j][h4*4+3] = a.w;
            float4 b = *reinterpret_cast<const float4*>(W1 + (256 + lane * 4 + j) * 16 + h4 * 4);
            w[4+j][h4*4+0] = b.x; w[4+j][h4*4+1] = b.y; w[4+j][h4*4+2] = b.z; w[4+j][h4*4+3] = b.w;
        }
    }

    const int l4 = lane & 15;
    const int hrev = ((l4 & 1) << 3) | ((l4 & 2) << 1) | ((l4 & 4) >> 1) | ((l4 & 8) >> 3);

    const float4* X4 = reinterpret_cast<const float4*>(X);

    int row = wave;
    if (row >= N) return;
    float4 xa = X4[(size_t)row * 128 + lane];
    float4 xb = X4[(size_t)row * 128 + 64 + lane];

    for (; row < N; row += nwave) {
        int nrow = row + nwave;
        float4 na, nb;
        if (nrow < N) {
            na = X4[(size_t)nrow * 128 + lane];
            nb = X4[(size_t)nrow * 128 + 64 + lane];
        }

        float a[16];
#pragma unroll
        for (int h = 0; h < 16; ++h) {
            a[h] = xa.x * w[0][h] + xa.y * w[1][h] + xa.z * w[2][h] + xa.w * w[3][h]
                 + xb.x * w[4][h] + xb.y * w[5][h] + xb.z * w[6][h] + xb.w * w[7][h];
        }

#define XW1_STEP(m, half)                                                  \
        {                                                                  \
            const bool hi_ = (lane & (m)) != 0;                            \
            _Pragma("unroll")                                              \
            for (int i = 0; i < (half); ++i) {                             \
                float send = hi_ ? a[i] : a[(half) + i];                   \
                float keep = hi_ ? a[(half) + i] : a[i];                   \
                a[i] = keep + __shfl_xor(send, (m));                       \
            }                                                              \
        }
        XW1_STEP(1, 8)
        XW1_STEP(2, 4)
        XW1_STEP(4, 2)
        XW1_STEP(8, 1)
#undef XW1_STEP
        a[0] += __shfl_xor(a[0], 16);
        a[0] += __shfl_xor(a[0], 32);

        if (lane < 16) XW1[(size_t)row * 16 + hrev] = a[0];

        xa = na; xb = nb;
    }
}

// Bucket SpMM (sort + pull) + relu+[W2|W3] epilogue. Writes the sorted
// bucket back to binned (block-exclusive segment) + lofs to lofs_g so
// k_spmm_out can skip the sort.
__global__ __launch_bounds__(1024)
void k_spmm_d23(uint2* __restrict__ binned, const int* __restrict__ bcur,
                int* __restrict__ lofs_g, const float* __restrict__ H,
                const float* __restrict__ W2, const float* __restrict__ W3,
                float* __restrict__ M, int N) {
    __shared__ uint2 se[CAP];
    __shared__ int lhist[BROWS];
    __shared__ int lofs[BROWS + 1];
    __shared__ int lrank[BROWS];
    const int b   = blockIdx.x;
    const int tid = threadIdx.x;

    if (tid < BROWS) { lhist[tid] = 0; lrank[tid] = 0; }
    __syncthreads();

    const int cnt = min(bcur[b], CAP);
    const uint2* eb = binned + (size_t)b * CAP;

    // stash + hist (CAP/1024 = 4.75 -> 5 static slots)
    uint2 st[5]; int slr[5];
#pragma unroll
    for (int it = 0; it < 5; ++it) {
        int j = tid + it * 1024;
        if (j < cnt) {
            uint2 e = nt_load_edge(&eb[j]);
            st[it] = e;
            slr[it] = (int)(e.x >> 17);
            atomicAdd(&lhist[slr[it]], 1);
        } else slr[it] = -1;
    }
    __syncthreads();

    if (tid < BROWS) lofs[tid + 1] = lhist[tid];
    if (tid == 0) lofs[0] = 0;
    __syncthreads();
    for (int off = 1; off < BROWS; off <<= 1) {
        int v = (tid < BROWS && tid >= off) ? lofs[tid + 1 - off] : 0;
        __syncthreads();
        if (tid < BROWS) lofs[tid + 1] += v;
        __syncthreads();
    }

#pragma unroll
    for (int it = 0; it < 5; ++it) {
        if (slr[it] >= 0) {
            int pos = lofs[slr[it]] + atomicAdd(&lrank[slr[it]], 1);
            se[pos] = st[it];
        }
    }
    __syncthreads();

    // persist sorted bucket + offsets for k_spmm_out
    uint2* wb = binned + (size_t)b * CAP;
#pragma unroll
    for (int it = 0; it < 5; ++it) {
        int j = tid + it * 1024;
        if (j < cnt) wb[j] = se[j];
    }
    if (tid <= BROWS) lofs_g[b * LOFS_STRIDE + tid] = lofs[tid];

    // register pull: 64 groups of 16 lanes; group g handles rows g, g+64
    const int f = tid & 15;
    const int g = tid >> 4;
    float wcol[16];
    if (f < 7) {
#pragma unroll
        for (int k = 0; k < 16; ++k) wcol[k] = W2[k * 7 + f];
    } else if (f < 14) {
#pragma unroll
        for (int k = 0; k < 16; ++k) wcol[k] = W3[k * 7 + (f - 7)];
    } else {
#pragma unroll
        for (int k = 0; k < 16; ++k) wcol[k] = 0.f;
    }
    const int rbase = b << SH;
#pragma unroll
    for (int rr = 0; rr < BROWS; rr += 64) {
        const int lr = rr + g;
        const int beg = lofs[lr], end = lofs[lr + 1];
        float acc = 0.f;
        for (int j = beg; j < end; ++j) {
            uint2 e = se[j];                       // LDS broadcast in group
            acc += __uint_as_float(e.y) * H[(size_t)(e.x & 0x1FFFF) * 16 + f];
        }
        float a = fmaxf(acc, 0.f);
        float o = 0.f;
#pragma unroll
        for (int k = 0; k < 16; ++k) o += __shfl(a, k, 16) * wcol[k];
        int row = rbase + lr;
        if (row < N) M[(size_t)row * 16 + f] = o;
    }
}

// Bucket SpMM (pre-sorted: copy + pull) + reparameterization epilogue.
__global__ __launch_bounds__(1024)
void k_spmm_out(const uint2* __restrict__ binned, const int* __restrict__ bcur,
                const int* __restrict__ lofs_g, const float* __restrict__ H,
                const float* __restrict__ eps, float* __restrict__ out, int N) {
    __shared__ uint2 se[CAP];
    __shared__ int lofs[BROWS + 1];
    const int b   = blockIdx.x;
    const int tid = threadIdx.x;

    if (tid <= BROWS) lofs[tid] = lofs_g[b * LOFS_STRIDE + tid];

    const int cnt = min(bcur[b], CAP);
    const uint2* eb = binned + (size_t)b * CAP;
#pragma unroll
    for (int it = 0; it < 5; ++it) {
        int j = tid + it * 1024;
        if (j < cnt) se[j] = nt_load_edge(&eb[j]);
    }
    __syncthreads();

    const int f = tid & 15;
    const int g = tid >> 4;
    const int rbase = b << SH;
#pragma unroll
    for (int rr = 0; rr < BROWS; rr += 64) {
        const int lr = rr + g;
        const int beg = lofs[lr], end = lofs[lr + 1];
        float acc = 0.f;
        for (int j = beg; j < end; ++j) {
            uint2 e = se[j];
            acc += __uint_as_float(e.y) * H[(size_t)(e.x & 0x1FFFF) * 16 + f];
        }
        const int src = (f < 7) ? (f + 7) : f;
        float ls = __shfl(acc, src, 16);
        int row = rbase + lr;
        if (row < N && f < 7) {
            out[(size_t)row * 7 + f] = acc + eps[(size_t)row * 7 + f] * __expf(ls);
        }
    }
}

extern "C" void kernel_launch(void* const* d_in, const int* in_sizes, int n_in,
                              void* d_out, int out_size, void* d_ws, size_t ws_size,
                              hipStream_t stream) {
    const float* X   = (const float*)d_in[0];
    const int*   er  = (const int*)d_in[1];
    const int*   ec  = (const int*)d_in[2];
    const float* ev  = (const float*)d_in[3];
    const float* W1  = (const float*)d_in[4];
    const float* W2  = (const float*)d_in[5];
    const float* W3  = (const float*)d_in[6];
    const float* eps = (const float*)d_in[7];
    float* out = (float*)d_out;

    const int N    = in_sizes[0] / 512;
    const int E    = in_sizes[1];
    const int nbkt = (N + BROWS - 1) >> SH;   // 782 for N=100000 (<= NBKT_MAX)

    // workspace layout
    float* ws     = (float*)d_ws;
    float* XW1    = ws;                                   // N*16 f32
    float* M23    = ws + (size_t)N * 16;                  // N*16 f32
    int*   bcur   = (int*)(ws + (size_t)N * 32);          // pad 1024 ints
    int*   lofs_g = bcur + 1024;                          // NBKT_MAX*LOFS_STRIDE ints
    uint2* binned = (uint2*)(lofs_g + NBKT_MAX * LOFS_STRIDE); // nbkt*CAP*8 B

    (void)hipMemsetAsync(bcur, 0, (size_t)nbkt * sizeof(int), stream);
    k_bin_xw1 <<<BINB + 2048, 256, 0, stream>>>(er, ec, ev, bcur, binned, E, nbkt,
                                                X, W1, XW1, N);
    k_spmm_d23<<<nbkt, 1024, 0, stream>>>(binned, bcur, lofs_g, XW1, W2, W3, M23, N);
    k_spmm_out<<<nbkt, 1024, 0, stream>>>(binned, bcur, lofs_g, M23, eps, out, N);
}

// Round 13
// 285.422 us; speedup vs baseline: 3.2019x; 1.0914x over previous
//
#include <hip/hip_runtime.h>
#include <hip/hip_fp16.h>

// VGAE encoder forward.
// R13: (a) UNFUSE bin/xw1 — R12 fusion gave one reg-alloc for both paths
// (VGPR 88 -> xw1's w[8][16] spilled) and (256,2) occupancy cap starved the
// bin path (21%). (b) fp16 gather tables: spmm FETCH=100MB showed ~0% L2 hit
// on H gathers (6.4MB f32 table > 4MiB XCD L2). XW1/M23 stored as __half ->
// 3.2MB table fits L2 -> gathers hit. (c) keep sort-once + nt edge loads.
//
// Stages: memset bcur | k_bin | k_xw1 | k_spmm_d23 | k_spmm_out

#define SH    7              // rows per bucket = 128
#define BROWS 128
#define NBKT_MAX 800         // runtime nbkt = (N+127)>>7 = 782 for N=100000
#define CAP   4864           // bucket capacity; mean 4092, sigma~64 -> +12 sigma
#define LOFS_STRIDE (BROWS + 4)

__device__ __forceinline__ uint2 nt_load_edge(const uint2* p) {
    unsigned long long v =
        __builtin_nontemporal_load(reinterpret_cast<const unsigned long long*>(p));
    return make_uint2((unsigned)v, (unsigned)(v >> 32));
}

// Bin edges by bucket = row>>SH. Two passes per block: LDS hist, one global
// atomicAdd per (block,bucket) to reserve, then placed writes.
__global__ __launch_bounds__(256)
void k_bin(const int* __restrict__ er, const int* __restrict__ ec,
           const float* __restrict__ ev, int* __restrict__ bcur,
           uint2* __restrict__ binned, int E, int nbkt) {
    __shared__ int lhist[NBKT_MAX];
    __shared__ int lbase[NBKT_MAX];
    __shared__ int lrank[NBKT_MAX];
    const int chunk = (E + gridDim.x - 1) / gridDim.x;
    const int lo = blockIdx.x * chunk;
    const int hi = min(lo + chunk, E);
    for (int t = threadIdx.x; t < nbkt; t += 256) { lhist[t] = 0; lrank[t] = 0; }
    __syncthreads();
    for (int e = lo + threadIdx.x; e < hi; e += 256)
        atomicAdd(&lhist[__builtin_nontemporal_load(&er[e]) >> SH], 1);
    __syncthreads();
    for (int t = threadIdx.x; t < nbkt; t += 256) {
        int n = lhist[t];
        lbase[t] = n ? atomicAdd(&bcur[t], n) : 0;
    }
    __syncthreads();
    for (int e = lo + threadIdx.x; e < hi; e += 256) {
        int r = __builtin_nontemporal_load(&er[e]);
        int b = r >> SH;
        int pos = lbase[b] + atomicAdd(&lrank[b], 1);
        if (pos < CAP) {
            int   c = __builtin_nontemporal_load(&ec[e]);
            float v = __builtin_nontemporal_load(&ev[e]);
            unsigned pack = ((unsigned)(r & (BROWS - 1)) << 17) | (unsigned)c;
            binned[(size_t)b * CAP + pos] = make_uint2(pack, __float_as_uint(v));
        }
    }
}

// XW1 = X @ W1, output fp16. Wave-per-row; lane L owns k {4L..4L+3, 256+4L..}.
__global__ __launch_bounds__(256, 2)
void k_xw1(const float* __restrict__ X, const float* __restrict__ W1,
           __half* __restrict__ out, int N) {
    const int lane = threadIdx.x & 63;
    const int wave  = (blockIdx.x * blockDim.x + threadIdx.x) >> 6;
    const int nwave = (gridDim.x * blockDim.x) >> 6;

    float w[8][16];
#pragma unroll
    for (int j = 0; j < 4; ++j) {
#pragma unroll
        for (int h4 = 0; h4 < 4; ++h4) {
            float4 a = *reinterpret_cast<const float4*>(W1 + (lane * 4 + j) * 16 + h4 * 4);
            w[j][h4*4+0] = a.x; w[j][h4*4+1] = a.y; w[j][h4*4+2] = a.z; w[j][h4*4+3] = a.w;
            float4 b = *reinterpret_cast<const float4*>(W1 + (256 + lane * 4 + j) * 16 + h4 * 4);
            w[4+j][h4*4+0] = b.x; w[4+j][h4*4+1] = b.y; w[4+j][h4*4+2] = b.z; w[4+j][h4*4+3] = b.w;
        }
    }

    const int l4 = lane & 15;
    const int hrev = ((l4 & 1) << 3) | ((l4 & 2) << 1) | ((l4 & 4) >> 1) | ((l4 & 8) >> 3);

    const float4* X4 = reinterpret_cast<const float4*>(X);

    int row = wave;
    if (row >= N) return;
    float4 xa = X4[(size_t)row * 128 + lane];
    float4 xb = X4[(size_t)row * 128 + 64 + lane];

    for (; row < N; row += nwave) {
        int nrow = row + nwave;
        float4 na, nb;
        if (nrow < N) {
            na = X4[(size_t)nrow * 128 + lane];
            nb = X4[(size_t)nrow * 128 + 64 + lane];
        }

        float a[16];
#pragma unroll
        for (int h = 0; h < 16; ++h) {
            a[h] = xa.x * w[0][h] + xa.y * w[1][h] + xa.z * w[2][h] + xa.w * w[3][h]
                 + xb.x * w[4][h] + xb.y * w[5][h] + xb.z * w[6][h] + xb.w * w[7][h];
        }

#define XW1_STEP(m, half_)                                                 \
        {                                                                  \
            const bool hi_ = (lane & (m)) != 0;                            \
            _Pragma("unroll")                                              \
            for (int i = 0; i < (half_); ++i) {                            \
                float send = hi_ ? a[i] : a[(half_) + i];                  \
                float keep = hi_ ? a[(half_) + i] : a[i];                  \
                a[i] = keep + __shfl_xor(send, (m));                       \
            }                                                              \
        }
        XW1_STEP(1, 8)
        XW1_STEP(2, 4)
        XW1_STEP(4, 2)
        XW1_STEP(8, 1)
#undef XW1_STEP
        a[0] += __shfl_xor(a[0], 16);
        a[0] += __shfl_xor(a[0], 32);

        if (lane < 16) out[(size_t)row * 16 + hrev] = __float2half(a[0]);

        xa = na; xb = nb;
    }
}

// Bucket SpMM (sort + pull, fp16 H) + relu+[W2|W3] epilogue (fp16 M out).
// Persists sorted bucket + lofs for k_spmm_out.
__global__ __launch_bounds__(1024)
void k_spmm_d23(uint2* __restrict__ binned, const int* __restrict__ bcur,
                int* __restrict__ lofs_g, const __half* __restrict__ H,
                const float* __restrict__ W2, const float* __restrict__ W3,
                __half* __restrict__ M, int N) {
    __shared__ uint2 se[CAP];
    __shared__ int lhist[BROWS];
    __shared__ int lofs[BROWS + 1];
    __shared__ int lrank[BROWS];
    const int b   = blockIdx.x;
    const int tid = threadIdx.x;

    if (tid < BROWS) { lhist[tid] = 0; lrank[tid] = 0; }
    __syncthreads();

    const int cnt = min(bcur[b], CAP);
    const uint2* eb = binned + (size_t)b * CAP;

    uint2 st[5]; int slr[5];
#pragma unroll
    for (int it = 0; it < 5; ++it) {
        int j = tid + it * 1024;
        if (j < cnt) {
            uint2 e = nt_load_edge(&eb[j]);
            st[it] = e;
            slr[it] = (int)(e.x >> 17);
            atomicAdd(&lhist[slr[it]], 1);
        } else slr[it] = -1;
    }
    __syncthreads();

    if (tid < BROWS) lofs[tid + 1] = lhist[tid];
    if (tid == 0) lofs[0] = 0;
    __syncthreads();
    for (int off = 1; off < BROWS; off <<= 1) {
        int v = (tid < BROWS && tid >= off) ? lofs[tid + 1 - off] : 0;
        __syncthreads();
        if (tid < BROWS) lofs[tid + 1] += v;
        __syncthreads();
    }

#pragma unroll
    for (int it = 0; it < 5; ++it) {
        if (slr[it] >= 0) {
            int pos = lofs[slr[it]] + atomicAdd(&lrank[slr[it]], 1);
            se[pos] = st[it];
        }
    }
    __syncthreads();

    // persist sorted bucket + offsets for k_spmm_out
    uint2* wb = binned + (size_t)b * CAP;
#pragma unroll
    for (int it = 0; it < 5; ++it) {
        int j = tid + it * 1024;
        if (j < cnt) wb[j] = se[j];
    }
    if (tid <= BROWS) lofs_g[b * LOFS_STRIDE + tid] = lofs[tid];

    // register pull (fp16 gather, L2-resident 3.2MB table)
    const int f = tid & 15;
    const int g = tid >> 4;
    float wcol[16];
    if (f < 7) {
#pragma unroll
        for (int k = 0; k < 16; ++k) wcol[k] = W2[k * 7 + f];
    } else if (f < 14) {
#pragma unroll
        for (int k = 0; k < 16; ++k) wcol[k] = W3[k * 7 + (f - 7)];
    } else {
#pragma unroll
        for (int k = 0; k < 16; ++k) wcol[k] = 0.f;
    }
    const int rbase = b << SH;
#pragma unroll
    for (int rr = 0; rr < BROWS; rr += 64) {
        const int lr = rr + g;
        const int beg = lofs[lr], end = lofs[lr + 1];
        float acc = 0.f;
        for (int j = beg; j < end; ++j) {
            uint2 e = se[j];                       // LDS broadcast in group
            acc += __uint_as_float(e.y) *
                   __half2float(H[(size_t)(e.x & 0x1FFFF) * 16 + f]);
        }
        float a = fmaxf(acc, 0.f);
        float o = 0.f;
#pragma unroll
        for (int k = 0; k < 16; ++k) o += __shfl(a, k, 16) * wcol[k];
        int row = rbase + lr;
        if (row < N) M[(size_t)row * 16 + f] = __float2half(o);
    }
}

// Bucket SpMM (pre-sorted: copy + pull, fp16 H) + reparameterization.
__global__ __launch_bounds__(1024)
void k_spmm_out(const uint2* __restrict__ binned, const int* __restrict__ bcur,
                const int* __restrict__ lofs_g, const __half* __restrict__ H,
                const float* __restrict__ eps, float* __restrict__ out, int N) {
    __shared__ uint2 se[CAP];
    __shared__ int lofs[BROWS + 1];
    const int b   = blockIdx.x;
    const int tid = threadIdx.x;

    if (tid <= BROWS) lofs[tid] = lofs_g[b * LOFS_STRIDE + tid];

    const int cnt = min(bcur[b], CAP);
    const uint2* eb = binned + (size_t)b * CAP;
#pragma unroll
    for (int it = 0; it < 5; ++it) {
        int j = tid + it * 1024;
        if (j < cnt) se[j] = nt_load_edge(&eb[j]);
    }
    __syncthreads();

    const int f = tid & 15;
    const int g = tid >> 4;
    const int rbase = b << SH;
#pragma unroll
    for (int rr = 0; rr < BROWS; rr += 64) {
        const int lr = rr + g;
        const int beg = lofs[lr], end = lofs[lr + 1];
        float acc = 0.f;
        for (int j = beg; j < end; ++j) {
            uint2 e = se[j];
            acc += __uint_as_float(e.y) *
                   __half2float(H[(size_t)(e.x & 0x1FFFF) * 16 + f]);
        }
        const int src = (f < 7) ? (f + 7) : f;
        float ls = __shfl(acc, src, 16);
        int row = rbase + lr;
        if (row < N && f < 7) {
            out[(size_t)row * 7 + f] = acc + eps[(size_t)row * 7 + f] * __expf(ls);
        }
    }
}

extern "C" void kernel_launch(void* const* d_in, const int* in_sizes, int n_in,
                              void* d_out, int out_size, void* d_ws, size_t ws_size,
                              hipStream_t stream) {
    const float* X   = (const float*)d_in[0];
    const int*   er  = (const int*)d_in[1];
    const int*   ec  = (const int*)d_in[2];
    const float* ev  = (const float*)d_in[3];
    const float* W1  = (const float*)d_in[4];
    const float* W2  = (const float*)d_in[5];
    const float* W3  = (const float*)d_in[6];
    const float* eps = (const float*)d_in[7];
    float* out = (float*)d_out;

    const int N    = in_sizes[0] / 512;
    const int E    = in_sizes[1];
    const int nbkt = (N + BROWS - 1) >> SH;   // 782 for N=100000 (<= NBKT_MAX)

    // workspace layout (halves first, then ints, then edge records)
    __half* XW1_h = (__half*)d_ws;                        // N*16 fp16 (3.2MB)
    __half* M23_h = XW1_h + (size_t)N * 16;               // N*16 fp16 (3.2MB)
    int*    bcur  = (int*)(M23_h + (size_t)N * 16);       // pad 1024 ints
    int*    lofs_g= bcur + 1024;                          // NBKT_MAX*LOFS_STRIDE
    uint2*  binned= (uint2*)(lofs_g + NBKT_MAX * LOFS_STRIDE); // nbkt*CAP*8B

    (void)hipMemsetAsync(bcur, 0, (size_t)nbkt * sizeof(int), stream);
    k_bin     <<<1024, 256, 0, stream>>>(er, ec, ev, bcur, binned, E, nbkt);
    k_xw1     <<<2048, 256, 0, stream>>>(X, W1, XW1_h, N);
    k_spmm_d23<<<nbkt, 1024, 0, stream>>>(binned, bcur, lofs_g, XW1_h, W2, W3, M23_h, N);
    k_spmm_out<<<nbkt, 1024, 0, stream>>>(binned, bcur, lofs_g, M23_h, eps, out, N);
}